// Round 9
// baseline (12742.677 us; speedup 1.0000x reference)
//
#include <hip/hip_runtime.h>
#include <math.h>

#define NB   16      // blocks
#define NTH  256     // threads per block
#define CH   128     // neurons per block (N/NB)
#define NN   2048    // N
#define DD   64      // D
#define TT   512     // T
#define KWTA 256
#define PA   65      // pad for [CH][64+1] rows (Dx, Dy)
#define PB   132     // pad for [64][128+4] rows (rho), comb access 2-way-free

typedef unsigned long long u64;

// ---- tagged cross-block data: (tag<<32)|valbits, double-buffered by parity --
// No barriers, no flags, no fences: consumers poll the data's own tags.
__device__ __align__(16) u64 g_xp[2][NN];       // unnormalized x_t
__device__ __align__(16) u64 g_rp[2][NB][DD];   // rho@x_un partials (f32)
__device__ __align__(16) u64 g_lp[2][NB][2];    // L1 partial (f64 as lo/hi pairs)
__device__ __align__(16) u64 g_yp[2][NN];       // y
__device__ __align__(16) float g_ET[NN*DD];     // E^T, staged at init (cached)

__global__ void bdh_init(const float* __restrict__ E) {
  const int gid = blockIdx.x * NTH + threadIdx.x;
  const int nthread = 64 * NTH;
  for (int k = gid; k < 2*NN; k += nthread) { ((u64*)g_xp)[k] = 0ull; ((u64*)g_yp)[k] = 0ull; }
  for (int k = gid; k < 2*NB*DD; k += nthread) ((u64*)g_rp)[k] = 0ull;
  if (gid < 2*NB*2) ((u64*)g_lp)[gid] = 0ull;
  for (int idx = gid; idx < NN * DD; idx += nthread) {
    const int n = idx >> 6, d = idx & 63;
    g_ET[idx] = E[(size_t)d * NN + n];
  }
}

__device__ __forceinline__ void st_pair(u64* p, unsigned valbits, unsigned tag) {
  __hip_atomic_store(p, ((u64)tag << 32) | (u64)valbits,
                     __ATOMIC_RELAXED, __HIP_MEMORY_SCOPE_AGENT);
}
__device__ __forceinline__ u64 ld_pair(const u64* p) {
  return __hip_atomic_load(p, __ATOMIC_RELAXED, __HIP_MEMORY_SCOPE_AGENT);
}

__device__ __forceinline__ double wredd(double v) {
  #pragma unroll
  for (int off = 32; off > 0; off >>= 1) v += __shfl_xor(v, off, 64);
  return v;
}
__device__ __forceinline__ float wredf(float v) {
  #pragma unroll
  for (int off = 32; off > 0; off >>= 1) v += __shfl_xor(v, off, 64);
  return v;
}

// poll 8 consecutive tagged pairs until all tags == want; returns value bits
__device__ __forceinline__ void poll8(const u64* __restrict__ p, unsigned want,
                                      unsigned* __restrict__ outb) {
  unsigned got = 0u;
  while (got != 0xffu) {
    #pragma unroll
    for (int j = 0; j < 8; ++j)
      if (!((got >> j) & 1u)) {
        const u64 w = ld_pair(&p[j]);
        if ((unsigned)(w >> 32) == want) { outb[j] = (unsigned)w; got |= 1u << j; }
      }
  }
}

// Exact top-K over 2048 nonnegative floats (bit patterns in keys[8]; key j of
// thread tid = element tid*8+j). Returns 8-bit keep mask (stable ties: lowest
// index first). Radix-256; 8-sub-banked atomic hist + bucket-owner reduce +
// wave-redundant in-register crossing detection (r5/r8-proven).
// PRE: hist[] zeroed on entry; POST: hist[] zeroed on exit.
__device__ __forceinline__ unsigned select_mask(const unsigned* __restrict__ keys,
                                                int K, int tid,
                                                unsigned* __restrict__ hist,  // [256*8]
                                                unsigned* __restrict__ hist2, // [256]
                                                unsigned* __restrict__ cw)    // [8]
{
  const int wv = tid >> 6, lane = tid & 63;
  const int sub = tid & 7;
  uint4* H4 = (uint4*)hist;
  const uint4 z4 = {0u, 0u, 0u, 0u};
  unsigned prefix = 0u, pmask = 0u;
  int remK = K;
  #pragma unroll
  for (int lev = 0; lev < 4; ++lev) {
    const int shf = 24 - 8 * lev;
    #pragma unroll
    for (int j = 0; j < 8; ++j)
      if ((keys[j] & pmask) == prefix)
        atomicAdd(&hist[(((keys[j] >> shf) & 255u) << 3) + sub], 1u);
    __syncthreads();
    {
      const uint4 a = H4[tid * 2], bq = H4[tid * 2 + 1];
      hist2[tid] = a.x + a.y + a.z + a.w + bq.x + bq.y + bq.z + bq.w;
      H4[tid * 2] = z4;
      H4[tid * 2 + 1] = z4;
    }
    __syncthreads();
    const uint4 cc = ((const uint4*)hist2)[lane];
    unsigned c[4] = {cc.x, cc.y, cc.z, cc.w};
    unsigned s[4];
    s[3] = c[3]; s[2] = c[2] + s[3]; s[1] = c[1] + s[2]; s[0] = c[0] + s[1];
    unsigned SS = s[0];
    #pragma unroll
    for (int off = 1; off < 64; off <<= 1) {
      const unsigned o = __shfl_down(SS, off, 64);
      if (lane + off < 64) SS += o;
    }
    const unsigned T = SS - s[0];
    unsigned pk = 0u;
    #pragma unroll
    for (int k = 0; k < 4; ++k) {
      const unsigned A = s[k] + T;
      if (A >= (unsigned)remK && (A - c[k]) < (unsigned)remK)
        pk = (((unsigned)(4 * lane + k)) << 16) | (unsigned)(remK - (int)(A - c[k]));
    }
    const unsigned long long bal = __ballot(pk != 0u);
    const int src = __ffsll((long long)bal) - 1;
    pk = __shfl(pk, src, 64);
    prefix |= (pk >> 16) << shf;
    remK = (int)(pk & 0xffffu);
    pmask |= 255u << shf;
  }
  const unsigned thr = prefix;
  const unsigned R = (unsigned)remK;
  unsigned lc[8], cnt = 0u;
  #pragma unroll
  for (int j = 0; j < 8; ++j) { lc[j] = cnt; cnt += (keys[j] == thr) ? 1u : 0u; }
  unsigned e = cnt;
  #pragma unroll
  for (int off = 1; off < 64; off <<= 1) {
    const unsigned o = __shfl_up(e, off, 64);
    if (lane >= off) e += o;
  }
  if (lane == 63) cw[wv] = e;
  __syncthreads();
  unsigned base = 0u;
  for (int w = 0; w < wv; ++w) base += cw[w];
  const unsigned excl = base + e - cnt;
  unsigned mask = 0u;
  #pragma unroll
  for (int j = 0; j < 8; ++j)
    if (keys[j] > thr || (keys[j] == thr && excl + lc[j] < R)) mask |= 1u << j;
  return mask;
}

__global__ void __launch_bounds__(NTH)
bdh_main(const int* __restrict__ tokens, const float* __restrict__ spike_u,
         const float* __restrict__ Emat, const float* __restrict__ Dx,
         const float* __restrict__ Dy, const float* __restrict__ temb,
         float* __restrict__ out)
{
  __shared__ float sh_rho[DD][PB];   // [d][local col]
  __shared__ float sh_Dx[CH][PA];    // [local neuron][d]
  __shared__ float sh_Dy[CH][PA];
  __shared__ int   sh_tok[TT];
  __shared__ float sh_v[2][DD];
  __shared__ float sh_xstate[CH];
  __shared__ float sh_xtun[CH];
  __shared__ float sh_ahat[DD];
  __shared__ float sh_ffac[CH];
  __shared__ unsigned sh_hist[256*8];
  __shared__ unsigned sh_hist2[256];
  __shared__ unsigned sh_cw[8];
  __shared__ float sh_fmisc[4];
  __shared__ double sh_dred[8];
  __shared__ float sh_gred[4][DD];
  __shared__ int   sh_aidx[KWTA];
  __shared__ float sh_aw[KWTA];

  const int tid  = threadIdx.x;
  const int b    = blockIdx.x;
  const int n0   = b * CH;
  const int i2   = tid >> 1;   // local neuron row (0..127), Dx/Dy mapping
  const int p2   = tid & 1;    // half-split of 64-dot
  const int d4   = tid >> 2;   // d row (0..63), rho mapping
  const int p4   = tid & 3;    // quarter-comb of 128-dot
  const int lane = tid & 63;
  const int wv   = tid >> 6;

  // ---- one-time init: tokens, rho=0, hist=0, weight slices -> LDS ----
  for (int k = tid; k < TT; k += NTH) sh_tok[k] = tokens[k];
  for (int k = tid; k < DD*PB; k += NTH) (&sh_rho[0][0])[k] = 0.0f;
  for (int k = tid; k < 256*8; k += NTH) sh_hist[k] = 0u;
  if (tid < CH) sh_xstate[tid] = 0.0f;
  for (int r = wv; r < CH; r += 4) {
    sh_Dx[r][lane] = Dx[(size_t)(n0 + r)*DD + lane];
    sh_Dy[r][lane] = Dy[(size_t)(n0 + r)*DD + lane];
  }
  __syncthreads();
  if (tid < DD) sh_v[0][tid] = temb[(size_t)sh_tok[0]*DD + tid];
  __syncthreads();

  for (int t = 0; t < TT; ++t) {
    const int par = t & 1;
    const unsigned want = (unsigned)(t + 1);

    // -------- phase 1: x_t (unnorm), L1 partial, rho@x partial ------------
    float spu = 0.0f;
    if (p2 == 0) spu = spike_u[(size_t)t*NN + n0 + i2];   // used in phase 2
    if (t + 1 < TT && tid < DD)
      sh_v[par ^ 1][tid] = temb[(size_t)sh_tok[t + 1]*DD + tid];

    float d1 = 0.0f;
    {
      const float* dxr = &sh_Dx[i2][p2*32];
      const float* vv  = &sh_v[par][p2*32];
      #pragma unroll
      for (int j = 0; j < 32; ++j) d1 += dxr[j] * vv[j];
    }
    d1 += __shfl_xor(d1, 1, 64);
    float xnew = 0.0f;
    if (p2 == 0) {
      xnew = 0.97f * sh_xstate[i2] + fmaxf(d1, 0.0f);
      sh_xtun[i2] = xnew;
      st_pair(&g_xp[par][n0 + i2], __float_as_uint(xnew), want);  // fire & forget
    }
    {
      double v = (p2 == 0) ? (double)fabsf(xnew) : 0.0;
      v = wredd(v);
      if (lane == 0) sh_dred[wv] = v;
      __syncthreads();
      if (tid == 0) {
        const double L = sh_dred[0] + sh_dred[1] + sh_dred[2] + sh_dred[3];
        const u64 lb = __double_as_longlong(L);
        st_pair(&g_lp[par][b][0], (unsigned)lb, want);
        st_pair(&g_lp[par][b][1], (unsigned)(lb >> 32), want);
      }
    }
    float qa = 0.0f;   // (rho @ x_un) partial over this block's 128 cols
    {
      const float* rr = &sh_rho[d4][0];
      #pragma unroll
      for (int j = 0; j < 32; ++j) { const int c = p4 + 4*j; qa += rr[c] * sh_xtun[c]; }
    }
    qa += __shfl_xor(qa, 1, 64);
    qa += __shfl_xor(qa, 2, 64);
    if (p4 == 0) st_pair(&g_rp[par][b][d4], __float_as_uint(qa), want);
    // NO barrier — consumers poll tags.

    // -------- phase 2: poll tagged x/L1 (all waves) + rf (wave 0) ---------
    // L1: lanes 0..15 of EVERY wave poll both halves (redundant, sync-free)
    double lv = 0.0;
    if (lane < 16) {
      unsigned got = 0u, lo = 0u, hi = 0u;
      while (got != 3u) {
        if (!(got & 1u)) { const u64 w = ld_pair(&g_lp[par][lane][0]);
          if ((unsigned)(w >> 32) == want) { lo = (unsigned)w; got |= 1u; } }
        if (!(got & 2u)) { const u64 w = ld_pair(&g_lp[par][lane][1]);
          if ((unsigned)(w >> 32) == want) { hi = (unsigned)w; got |= 2u; } }
      }
      lv = __longlong_as_double(((u64)hi << 32) | (u64)lo);
    }
    const double L1tot = wredd(lv);          // same 64-lane tree as before
    const float Lden = (float)L1tot + 1e-6f;
    // x: every thread polls its 8 pairs
    unsigned xub[8];
    poll8(&g_xp[par][tid*8], want, xub);
    unsigned xkeys[8];                        // identical in every block
    #pragma unroll
    for (int j = 0; j < 8; ++j)
      xkeys[j] = __float_as_uint(__uint_as_float(xub[j]) / Lden);
    if (wv == 0) {
      // rf: 16 tagged partials for d = lane
      float rv[16];
      unsigned got = 0u;
      while (got != 0xffffu) {
        #pragma unroll
        for (int bb = 0; bb < 16; ++bb)
          if (!((got >> bb) & 1u)) {
            const u64 w = ld_pair(&g_rp[par][bb][lane]);
            if ((unsigned)(w >> 32) == want) { rv[bb] = __uint_as_float((unsigned)w); got |= 1u << bb; }
          }
      }
      // sum in r8's exact grouping: ((g0+g1)+g2)+g3, each g = 0.0+v0+v1+v2+v3
      double a0 = 0.0, a1 = 0.0, a2 = 0.0, a3 = 0.0;
      #pragma unroll
      for (int j = 0; j < 4; ++j) a0 += (double)rv[j];
      #pragma unroll
      for (int j = 4; j < 8; ++j) a1 += (double)rv[j];
      #pragma unroll
      for (int j = 8; j < 12; ++j) a2 += (double)rv[j];
      #pragma unroll
      for (int j = 12; j < 16; ++j) a3 += (double)rv[j];
      const double qd = ((a0 + a1) + a2) + a3;
      const float rf = (float)qd / Lden;
      const float mm = wredf(rf) * (1.0f/64.0f);
      const float dv = rf - mm;
      const float sd = sqrtf(wredf(dv*dv) * (1.0f/63.0f));   // ddof=1
      sh_ahat[lane] = dv / (sd + 1e-6f);
    }
    __syncthreads();                          // a_hat ready for all waves
    float d2 = 0.0f;
    {
      const float* dyr = &sh_Dy[i2][p2*32];
      const float* aa  = &sh_ahat[p2*32];
      #pragma unroll
      for (int j = 0; j < 32; ++j) d2 += dyr[j] * aa[j];
    }
    d2 += __shfl_xor(d2, 1, 64);
    if (p2 == 0) {
      const float sp = fmaxf(d2, 0.0f) + log1pf(expf(-fabsf(d2)));  // softplus
      st_pair(&g_yp[par][n0 + i2],
              __float_as_uint(sp + ((spu < 0.01f) ? 1.0f : 0.0f)), want);
    }
    // NO barrier.

    // -------- phase 3: poll y, selects, gather, update --------------------
    unsigned ykeys[8];
    poll8(&g_yp[par][tid*8], want, ykeys);
    // k-WTA keep mask for this thread's 8 global positions
    const unsigned km = select_mask(ykeys, KWTA, tid, sh_hist, sh_hist2, sh_cw);
    // y_t products + nonzero flags (y > 0 always; nz iff kept and x > 0)
    float p[8]; unsigned nzm = 0u;
    #pragma unroll
    for (int j = 0; j < 8; ++j) {
      const float yv = __uint_as_float(ykeys[j]);
      const float xv = __uint_as_float(xkeys[j]);
      p[j] = yv * xv;
      if (((km >> j) & 1u) && xv > 0.0f) nzm |= 1u << j;
    }
    const unsigned cnt = (unsigned)__popc(nzm);
    // s = sum(y_t) (f64), and compaction offsets — one shared sync
    {
      double sp = 0.0;
      #pragma unroll
      for (int j = 0; j < 8; ++j) if ((nzm >> j) & 1u) sp += (double)p[j];
      sp = wredd(sp);
      if (lane == 0) sh_dred[wv] = sp;
    }
    unsigned e = cnt;
    #pragma unroll
    for (int off = 1; off < 64; off <<= 1) {
      const unsigned o = __shfl_up(e, off, 64);
      if (lane >= off) e += o;
    }
    if (lane == 63) sh_cw[4 + wv] = e;
    __syncthreads();
    const float sf = (float)(sh_dred[0] + sh_dred[1] + sh_dred[2] + sh_dred[3]);
    const float scale = (sf > 1e-8f) ? fminf(1.0f, 1.0f/(sf + 1e-8f)) : 1.0f;
    const int m = (int)(sh_cw[4] + sh_cw[5] + sh_cw[6] + sh_cw[7]);
    {
      unsigned base = 0u;
      for (int w = 0; w < wv; ++w) base += sh_cw[4 + w];
      int pos = (int)(base + e - cnt);
      #pragma unroll
      for (int j = 0; j < 8; ++j)
        if ((nzm >> j) & 1u) { sh_aidx[pos] = 8*tid + j; sh_aw[pos] = scale * p[j]; ++pos; }
    }
    __syncthreads();
    // sparse gather-matvec: v_pre[d] = sum_i w_i * ET[idx_i][d]; 4 ILP chains
    {
      float a0 = 0.0f, a1 = 0.0f, a2 = 0.0f, a3 = 0.0f;
      int i = wv;
      for (; i + 12 < m; i += 16) {
        a0 = fmaf(sh_aw[i],      g_ET[(size_t)sh_aidx[i]     *DD + lane], a0);
        a1 = fmaf(sh_aw[i + 4],  g_ET[(size_t)sh_aidx[i + 4] *DD + lane], a1);
        a2 = fmaf(sh_aw[i + 8],  g_ET[(size_t)sh_aidx[i + 8] *DD + lane], a2);
        a3 = fmaf(sh_aw[i + 12], g_ET[(size_t)sh_aidx[i + 12]*DD + lane], a3);
      }
      for (; i < m; i += 4)
        a0 = fmaf(sh_aw[i], g_ET[(size_t)sh_aidx[i]*DD + lane], a0);
      sh_gred[wv][lane] = (a0 + a1) + (a2 + a3);
    }
    __syncthreads();
    // LN + entropy + gain (wave 0), all blocks redundantly -> identical
    if (tid < 64) {
      const float z = sh_gred[0][tid] + sh_gred[1][tid] + sh_gred[2][tid] + sh_gred[3][tid];
      const float mn = wredf(z) * (1.0f/64.0f);
      const float dv = z - mn;
      const float sd = sqrtf(wredf(dv*dv) * (1.0f/63.0f));
      const float vs = dv / (sd + 1e-6f);
      if (b == 0) out[t*DD + tid] = vs;
      float mx = vs;
      #pragma unroll
      for (int off = 32; off > 0; off >>= 1) mx = fmaxf(mx, __shfl_xor(mx, off, 64));
      const float ex = expf(vs - mx);
      const float se = wredf(ex);
      const float pp = ex / se;
      const float ht = wredf(-pp * logf(pp + 1e-12f));
      if (tid == 0) sh_fmisc[0] = fminf(1.0f, ht / logf(64.0f));
    }
    __syncthreads();
    const float gain = sh_fmisc[0];
    int kdi = (int)(2048.0f * (0.05f + 0.25f * gain));
    kdi = kdi < 1 ? 1 : (kdi > NN ? NN : kdi);
    // dynamic top-k on x; apply mask to local columns only
    const unsigned xm = select_mask(xkeys, kdi, tid, sh_hist, sh_hist2, sh_cw);
    #pragma unroll
    for (int j = 0; j < 8; ++j) {
      const int g = 8*tid + j;
      const unsigned l = (unsigned)(g - n0);
      if (l < (unsigned)CH) {
        const float xv = __uint_as_float(xkeys[j]);
        const float v = ((xm >> j) & 1u) ? xv : 0.0f;
        sh_xstate[l] = v;
        sh_ffac[l] = (v <= 0.0f) ? (1.0f - 0.01f) : 1.0f;
      }
    }
    __syncthreads();
    {
      const float vd = sh_v[par][d4];
      float* rr = &sh_rho[d4][0];
      #pragma unroll
      for (int j = 0; j < 32; ++j) {
        const int c = p4 + 4*j;
        rr[c] = 0.97f * (rr[c]*sh_ffac[c] + gain * (vd * sh_xstate[c]));
      }
    }
    __syncthreads();   // protect sh_v/sh_xstate/rho before next iteration
  }
}

extern "C" void kernel_launch(void* const* d_in, const int* in_sizes, int n_in,
                              void* d_out, int out_size, void* d_ws, size_t ws_size,
                              hipStream_t stream) {
  const int*   tokens = (const int*)d_in[0];
  const float* spike  = (const float*)d_in[1];
  const float* Emat   = (const float*)d_in[2];
  const float* Dx     = (const float*)d_in[3];
  const float* Dy     = (const float*)d_in[4];
  const float* temb   = (const float*)d_in[5];
  float* out = (float*)d_out;
  (void)in_sizes; (void)n_in; (void)out_size; (void)d_ws; (void)ws_size;
  bdh_init<<<dim3(64), dim3(NTH), 0, stream>>>(Emat);
  bdh_main<<<dim3(NB), dim3(NTH), 0, stream>>>(tokens, spike, Emat, Dx, Dy, temb, out);
}